// Round 5
// baseline (192.093 us; speedup 1.0000x reference)
//
#include <hip/hip_runtime.h>

#define TW 512        // output tile width (2 cols per thread)
#define TH 6          // output tile height (small -> 6 blocks/CU)
#define IH 12         // TH + 6 staged input rows
#define IWP 520       // TW + 6 cols, padded to float4 multiple
#define NV4 (IWP/4)   // 130 float4 slots per row
#define W_IN 4096
#define H_IN 4096
#define W_OUT 4090
#define H_OUT 4090

__global__ __launch_bounds__(256, 6) void conv7x7(
    const float* __restrict__ x, const float* __restrict__ wgt,
    const float* __restrict__ bias, float* __restrict__ out)
{
    __shared__ float tile[IH][IWP];   // 12*520*4 = 24,960 B -> 6 blocks/CU

    const int tx = threadIdx.x;
    const int x0 = blockIdx.x * TW;
    const int y0 = blockIdx.y * TH;

    // ---- weights + bias (wave-uniform addresses -> scalarized) ----
    float W[49];
    #pragma unroll
    for (int i = 0; i < 49; ++i) W[i] = wgt[i];
    const float bb = bias[0];

    // ---- stage input tile: coalesced float4 loads ----
    const int NSLOT = IH * NV4;       // 1560
    #pragma unroll
    for (int it = 0; it < (NSLOT + 255) / 256; ++it) {
        const int slot = it * 256 + tx;
        if (slot < NSLOT) {
            const int r  = slot / NV4;    // const divisor -> magic mul
            const int c4 = slot - r * NV4;
            const int gy = y0 + r;
            const int gx = x0 + c4 * 4;
            float4 v;
            if (gy < H_IN && gx + 3 < W_IN) {
                v = *reinterpret_cast<const float4*>(x + (size_t)gy * W_IN + gx);
            } else {
                v.x = (gy < H_IN && gx + 0 < W_IN) ? x[(size_t)gy * W_IN + gx + 0] : 0.f;
                v.y = (gy < H_IN && gx + 1 < W_IN) ? x[(size_t)gy * W_IN + gx + 1] : 0.f;
                v.z = (gy < H_IN && gx + 2 < W_IN) ? x[(size_t)gy * W_IN + gx + 2] : 0.f;
                v.w = (gy < H_IN && gx + 3 < W_IN) ? x[(size_t)gy * W_IN + gx + 3] : 0.f;
            }
            *reinterpret_cast<float4*>(&tile[r][c4 * 4]) = v;
        }
    }
    __syncthreads();

    // ---- compute: 2 cols/thread, ring of 6 accumulators, all-static ----
    const int cx = 2 * tx;            // local column of first output
    const int gx = x0 + cx;           // global column of first output

    float a0[TH], a1[TH];
    #pragma unroll
    for (int s = 0; s < TH; ++s) { a0[s] = 0.f; a1[s] = 0.f; }

    #pragma unroll
    for (int r = 0; r < IH; ++r) {
        // window: 8 consecutive floats at cx (8B-aligned -> ds_read_b64 x4)
        float2 p0 = *reinterpret_cast<const float2*>(&tile[r][cx + 0]);
        float2 p1 = *reinterpret_cast<const float2*>(&tile[r][cx + 2]);
        float2 p2 = *reinterpret_cast<const float2*>(&tile[r][cx + 4]);
        float2 p3 = *reinterpret_cast<const float2*>(&tile[r][cx + 6]);
        const float f[8] = { p0.x, p0.y, p1.x, p1.y, p2.x, p2.y, p3.x, p3.y };

        #pragma unroll
        for (int ky = 0; ky < 7; ++ky) {
            const int oy = r - ky;            // static
            if (oy >= 0 && oy < TH) {         // static predicate
                const int s = oy % TH;        // static ring slot
                #pragma unroll
                for (int kx = 0; kx < 7; ++kx) {
                    a0[s] += W[ky * 7 + kx] * f[kx];
                    a1[s] += W[ky * 7 + kx] * f[kx + 1];
                }
            }
        }

        const int oy = r - 6;                 // output row completed by row r
        if (oy >= 0) {                        // static; oy < TH always (r <= 11)
            const int s = oy % TH;            // static
            const int gy = y0 + oy;
            if (gy < H_OUT) {
                if (gx + 1 < W_OUT) {
                    float2 o; o.x = a0[s] + bb; o.y = a1[s] + bb;
                    *reinterpret_cast<float2*>(&out[(size_t)gy * W_OUT + gx]) = o;
                } else if (gx < W_OUT) {
                    out[(size_t)gy * W_OUT + gx] = a0[s] + bb;
                }
            }
            a0[s] = 0.f; a1[s] = 0.f;
        }
    }
}

extern "C" void kernel_launch(void* const* d_in, const int* in_sizes, int n_in,
                              void* d_out, int out_size, void* d_ws, size_t ws_size,
                              hipStream_t stream) {
    const float* x = (const float*)d_in[0];
    const float* w = (const float*)d_in[1];
    const float* b = (const float*)d_in[2];
    float* out = (float*)d_out;
    // x: ceil(4090/512)=8 ; y: ceil(4090/6)=682
    dim3 grid(8, 682);
    conv7x7<<<grid, 256, 0, stream>>>(x, w, b, out);
}

// Round 6
// 57.460 us; speedup vs baseline: 3.3431x; 3.3431x over previous
//
#include <hip/hip_runtime.h>

#define WI 4096
#define HI 4096
#define WO 4090
#define HO 4090
#define SLOTW 520          // floats per ring slot (need 518, pad to 16B mult)
#define RING 16            // ring rows; groups of 4, never wraps mid-group
#define SEGROWS 32         // output rows per block
#define SLOTB (SLOTW*4)

__device__ __forceinline__ void gl_lds16(const float* g, float* l) {
    __builtin_amdgcn_global_load_lds(
        (const __attribute__((address_space(1))) void*)g,
        (__attribute__((address_space(3))) void*)l, 16, 0, 0);
}

// One 4-row step. TC = compile-time t representative (exact for peeled steps;
// parity representative 2/3 for the main loop: (4*TC+j-ky)&7 == (4*t+j-ky)&7
// since 4t mod 8 depends only on t&1). TR = runtime t (LDS slots, row ids).
#define STEP(TC, TR)                                                        \
  {                                                                         \
    const int sb_ = (4*(TR)) & 15;                                          \
    _Pragma("unroll")                                                       \
    for (int j = 0; j < 4; ++j) {                                           \
      const float* lrow_ = ring + (sb_ + j) * SLOTW + 2 * tid;              \
      const float2 q0 = *(const float2*)(lrow_ + 0);                        \
      const float2 q1 = *(const float2*)(lrow_ + 2);                        \
      const float2 q2 = *(const float2*)(lrow_ + 4);                        \
      const float2 q3 = *(const float2*)(lrow_ + 6);                        \
      const float f_[8] = {q0.x,q0.y,q1.x,q1.y,q2.x,q2.y,q3.x,q3.y};        \
      _Pragma("unroll")                                                     \
      for (int ky = 0; ky < 7; ++ky) {                                      \
        if (4*(TC) + j - ky >= 0) {          /* static */                   \
          const int s_ = (4*(TC) + j - ky) & 7;                             \
          _Pragma("unroll")                                                 \
          for (int kx = 0; kx < 7; ++kx) {                                  \
            const float w_ = Wt[ky*7 + kx];                                 \
            a0[s_] += w_ * f_[kx];                                          \
            a1[s_] += w_ * f_[kx + 1];                                      \
          }                                                                 \
        }                                                                   \
      }                                                                     \
      if (4*(TC) + j - 6 >= 0) {             /* static: store exists */     \
        const int ss_  = (4*(TC) + j - 6) & 7;                              \
        const int oyl_ = 4*(TR) + j - 6;                                    \
        const int gy_  = gy0 + oyl_;                                        \
        if (oyl_ < SEGROWS && gy_ < HO) {                                   \
          if (gx + 1 < WO) {                                                \
            float2 o_; o_.x = a0[ss_] + bb; o_.y = a1[ss_] + bb;            \
            *(float2*)(out + (size_t)gy_ * WO + gx) = o_;                   \
          }                                                                 \
        }                                                                   \
        a0[ss_] = 0.f; a1[ss_] = 0.f;                                       \
      }                                                                     \
    }                                                                       \
  }

__global__ __launch_bounds__(256, 4) void conv7x7(
    const float* __restrict__ x, const float* __restrict__ wgt,
    const float* __restrict__ bias, float* __restrict__ out)
{
    __shared__ float ring[RING * SLOTW];   // 33,280 B -> 4 blocks/CU

    const int tid = threadIdx.x;
    const int x0  = blockIdx.x * 512;      // stripe start col (floats)
    const int gy0 = blockIdx.y * SEGROWS;  // first output row of segment
    const int gx  = x0 + 2 * tid;

    // weights + bias: uniform addresses -> SGPR-resident
    float Wt[49];
    #pragma unroll
    for (int i = 0; i < 49; ++i) Wt[i] = wgt[i];
    const float bb = bias[0];

    // --- staging chunk precompute: 520 16B-chunks per 4-row group ---
    // chunk c -> local row j = c/130, col-offset off = c%130
    const int c1 = tid + 256, c2 = tid + 512;
    const int j0 = tid / 130, j1 = c1 / 130, j2 = 3;
    int o0 = tid - j0 * 130, o1 = c1 - j1 * 130, o2 = c2 - 390;
    // right-edge clamp: cols >= WI never feed valid outputs; read col 0 instead
    o0 = (x0 + o0 * 4 + 3 < WI) ? o0 : 0;
    o1 = (x0 + o1 * 4 + 3 < WI) ? o1 : 0;
    o2 = (x0 + o2 * 4 + 3 < WI) ? o2 : 0;

    // stage group g (input rows gy0+4g .. +3) into ring slots (4g&15)..+3
    auto STAGE = [&](int g) {
        const int gb = ((4 * g) & 15) * SLOTW;   // group base (floats)
        const int rb = gy0 + 4 * g;
        int r0 = rb + j0; r0 = r0 < HI ? r0 : HI - 1;
        int r1 = rb + j1; r1 = r1 < HI ? r1 : HI - 1;
        gl_lds16(x + (size_t)r0 * WI + x0 + o0 * 4, ring + gb + tid * 4);
        gl_lds16(x + (size_t)r1 * WI + x0 + o1 * 4, ring + gb + c1 * 4);
        if (tid < 8) {
            int r2 = rb + 3; r2 = r2 < HI ? r2 : HI - 1;
            gl_lds16(x + (size_t)r2 * WI + x0 + o2 * 4, ring + gb + c2 * 4);
        }
    };

    float a0[8], a1[8];
    #pragma unroll
    for (int s = 0; s < 8; ++s) { a0[s] = 0.f; a1[s] = 0.f; }

    // prologue: 3 groups in flight
    STAGE(0); STAGE(1); STAGE(2);
    __syncthreads();                 // vmcnt(0): groups 0-2 resident

    STAGE(3); STEP(0, 0);
    __syncthreads();
    STAGE(4); STEP(1, 1);
    __syncthreads();

    for (int u = 1; u < 5; ++u) {
        const int t0 = 2 * u;
        if (t0 + 3 <= 9) STAGE(t0 + 3);
        STEP(2, t0);                 // parity 0 representative
        __syncthreads();
        const int t1 = 2 * u + 1;
        if (t1 + 3 <= 9) STAGE(t1 + 3);
        STEP(3, t1);                 // parity 1 representative
        __syncthreads();
    }
}

extern "C" void kernel_launch(void* const* d_in, const int* in_sizes, int n_in,
                              void* d_out, int out_size, void* d_ws, size_t ws_size,
                              hipStream_t stream) {
    const float* x = (const float*)d_in[0];
    const float* w = (const float*)d_in[1];
    const float* b = (const float*)d_in[2];
    float* out = (float*)d_out;
    // 8 column stripes x 128 row segments = 1024 blocks = exactly 4/CU
    dim3 grid(8, 128);
    conv7x7<<<grid, 256, 0, stream>>>(x, w, b, out);
}